// Round 9
// baseline (179.773 us; speedup 1.0000x reference)
//
#include <hip/hip_runtime.h>
#include <math.h>

#define NB 16
#define NC 256
#define NHW 1024
#define NE 512
#define NDQ 4
#define NLQ 4
#define NQB 6
#define QDIM 64
#define PIX 8      // pixels per (single-wave) k_main block
#define XPAD 260   // xs row stride (floats)

typedef float v2f __attribute__((ext_vector_type(2)));

// ======== constexpr circuit algebra (CNOT ring is GF(2)-linear) ========
constexpr int fwd1(int i) {
    int r = i;
    for (int c = 0; c < NQB; ++c) {
        int t = (c + 1) % NQB;
        if ((r >> (NQB - 1 - c)) & 1) r ^= 1 << (NQB - 1 - t);
    }
    return r;
}
constexpr int fwdl(int s, int l) { for (int i = 0; i < l; ++i) s = fwd1(s); return s; }
constexpr int parity6(int x) { x ^= x >> 4; x ^= x >> 2; x ^= x >> 1; return x & 1; }

// Gate (l,q) acts on storage pairs (s, s^M), M = f^{-l}(2^(5-q)); "hi" element
// iff parity(s & V); measurement sign for data qubit d: -1 iff parity(s & W[d]).
// (Machinery verified end-to-end by R8's passing run.)
struct GateTab { int M[NLQ][NQB]; int V[NLQ][NQB]; int W[NDQ]; };
constexpr GateTab make_tab() {
    GateTab g{};
    for (int l = 0; l < NLQ; ++l)
        for (int q = 0; q < NQB; ++q) {
            int m = 1 << (NQB - 1 - q);
            for (int x = 0; x < QDIM; ++x) if (fwdl(x, l) == m) { g.M[l][q] = x; break; }
            int V = 0;
            for (int t = 0; t < NQB; ++t) V |= ((fwdl(1 << t, l) >> (NQB - 1 - q)) & 1) << t;
            g.V[l][q] = V;
        }
    for (int d = 0; d < NDQ; ++d) {
        int W = 0;
        for (int t = 0; t < NQB; ++t) W |= ((fwdl(1 << t, NLQ) >> (NQB - 1 - d)) & 1) << t;
        g.W[d] = W;
    }
    return g;
}
constexpr GateTab GT = make_tab();

// ---- Kernel 1: fused GroupNorm stats (blk<512) + style matvec (blk>=512) ----
__global__ __launch_bounds__(256) void k_pre(const float* __restrict__ x,
                                             const float* __restrict__ emb,
                                             const float* __restrict__ w_style,
                                             const float* __restrict__ b_style,
                                             const float* __restrict__ theta,
                                             float* __restrict__ mu,
                                             float* __restrict__ rs,
                                             float* __restrict__ A) {
    if (blockIdx.x < 512) {
        int bg = blockIdx.x;
        const float4* xp = (const float4*)(x + (size_t)bg * 8 * NHW);
        float s = 0.f, ss = 0.f;
        for (int i = threadIdx.x; i < 8 * NHW / 4; i += 256) {
            float4 v = xp[i];
            s  += v.x + v.y + v.z + v.w;
            ss += v.x*v.x + v.y*v.y + v.z*v.z + v.w*v.w;
        }
        __shared__ float red0[4], red1[4];
        #pragma unroll
        for (int o = 32; o; o >>= 1) { s += __shfl_down(s, o); ss += __shfl_down(ss, o); }
        int lane = threadIdx.x & 63, w = threadIdx.x >> 6;
        if (lane == 0) { red0[w] = s; red1[w] = ss; }
        __syncthreads();
        if (threadIdx.x == 0) {
            s  = red0[0] + red0[1] + red0[2] + red0[3];
            ss = red1[0] + red1[1] + red1[2] + red1[3];
            float m = s * (1.f / 8192.f);
            float var = ss * (1.f / 8192.f) - m * m;
            mu[bg] = m;
            rs[bg] = rsqrtf(var + 1e-5f);
        }
    } else {
        int b = blockIdx.x - 512;
        __shared__ float es[NE];
        int t = threadIdx.x;
        for (int i = t; i < NE; i += 256) {
            float v = emb[b * NE + i];
            es[i] = v / (1.f + __expf(-v));
        }
        __syncthreads();
        int j0 = t >> 3, sub = t & 7;
        for (int pass = 0; pass < 6; ++pass) {
            int j = pass * 32 + j0;
            const float* wr = w_style + (size_t)j * NE + sub * 64;
            const float* er = es + sub * 64;
            float acc = 0.f;
            #pragma unroll
            for (int i = 0; i < 64; i += 4) {
                float4 w4 = *(const float4*)(wr + i);
                acc = fmaf(w4.x, er[i],   acc);
                acc = fmaf(w4.y, er[i+1], acc);
                acc = fmaf(w4.z, er[i+2], acc);
                acc = fmaf(w4.w, er[i+3], acc);
            }
            acc += __shfl_xor(acc, 1);
            acc += __shfl_xor(acc, 2);
            acc += __shfl_xor(acc, 4);
            if (sub == 0) A[b * 192 + j] = theta[j] + b_style[j] + acc;
        }
    }
}

// ---- Kernel 2: SINGLE-WAVE blocks. grid = 2048 x 64 thr, 8 indep blocks/CU ----
// __syncthreads in a 1-wave workgroup is ~free -> phases of different blocks
// slide freely (no grid-wide lockstep). (64,2): VGPR cap 256, no spill.
__global__ __launch_bounds__(64, 2) void k_main(
    const float* __restrict__ x,
    const float* __restrict__ gamma,
    const float* __restrict__ beta,
    const float* __restrict__ w_in,
    const float* __restrict__ b_in,
    const float* __restrict__ A,
    const float* __restrict__ w_out,
    const float* __restrict__ b_out,
    const float* __restrict__ mu,
    const float* __restrict__ rs,
    float* __restrict__ out) {

    __shared__ float xs[PIX * XPAD];  // [p][c]: normalized h, later raw-x; 8.3 KB
    __shared__ float as_[PIX * 36];   // ang [p][o], later meas [p][o]; 1.2 KB

    // XCD-pairing swizzle: blocks 2t,2t+1 (two 32-B halves of the same 64-B
    // lines) land on the same XCD under the i%8 round-robin dispatch heuristic.
    int i = blockIdx.x;
    int tile = 2 * (i & 7) + 16 * (i >> 4) + ((i >> 3) & 1);
    int b = tile >> 7;
    int pbase = (tile & 127) * PIX;
    int t = threadIdx.x;

    // ---- P0: load 8px x 256ch tile to registers (only x read here) ----
    int cidx = t >> 1, p4 = (t & 1) * 4;
    float4 xr[8];
    #pragma unroll
    for (int k = 0; k < 8; ++k) {
        int c = cidx + 32 * k;
        xr[k] = *(const float4*)(x + (size_t)(b * NC + c) * NHW + pbase + p4);
    }

    // ---- P1: normalize -> xs[p][c] ----
    #pragma unroll
    for (int k = 0; k < 8; ++k) {
        int c = cidx + 32 * k;
        int g = b * 32 + (c >> 3);
        float sc = rs[g] * gamma[c];
        float sh = fmaf(-mu[g], sc, beta[c]);
        float4 v = xr[k];
        float* bp = xs + p4 * XPAD + c;
        bp[0]        = fmaf(v.x, sc, sh);
        bp[XPAD]     = fmaf(v.y, sc, sh);
        bp[2 * XPAD] = fmaf(v.z, sc, sh);
        bp[3 * XPAD] = fmaf(v.w, sc, sh);
    }
    __syncthreads();

    // ---- P2: ang[p][o] = w_in[o].h[p] + b_in[o]; lane=(p=t>>3, og=t&7) ----
    {
        int p = t >> 3, og = t & 7;
        int o0 = og * 4;
        const float* hrow = xs + p * XPAD;
        v2f acc[4] = {{0.f,0.f},{0.f,0.f},{0.f,0.f},{0.f,0.f}};
        #pragma unroll 8
        for (int c = 0; c < NC; c += 4) {
            float4 h = *(const float4*)(hrow + c);
            v2f hlo = {h.x, h.y}, hhi = {h.z, h.w};
            #pragma unroll
            for (int r = 0; r < 4; ++r) {
                float4 w = *(const float4*)(w_in + (o0 + r) * NC + c);
                acc[r] = __builtin_elementwise_fma((v2f){w.x, w.y}, hlo, acc[r]);
                acc[r] = __builtin_elementwise_fma((v2f){w.z, w.w}, hhi, acc[r]);
            }
        }
        float4 bi = *(const float4*)(b_in + o0);
        float4 r4 = {acc[0].x + acc[0].y + bi.x, acc[1].x + acc[1].y + bi.y,
                     acc[2].x + acc[2].y + bi.z, acc[3].x + acc[3].y + bi.w};
        *(float4*)(as_ + p * 36 + o0) = r4;
    }
    __syncthreads();

    // ---- stash raw x over xs (P2 consumed normalized copy) ----
    #pragma unroll
    for (int k = 0; k < 8; ++k) {
        int c = cidx + 32 * k;
        float4 v = xr[k];
        float* bp = xs + p4 * XPAD + c;
        bp[0] = v.x; bp[XPAD] = v.y; bp[2 * XPAD] = v.z; bp[3 * XPAD] = v.w;
    }
    __syncthreads();

    // ---- P3: circuits, 1 lane per circuit (g = t>>3, p = t&7), perm-free ----
    {
        int g = t >> 3, p = t & 7;
        float4 angv = *(const float4*)(as_ + p * 36 + g * 4);
        float angp[NDQ] = {angv.x, angv.y, angv.z, angv.w};
        float Ar[24];
        {
            const float4* Ab4 = (const float4*)(A + b * 192 + g * 24);
            #pragma unroll
            for (int j = 0; j < 6; ++j) {
                float4 a4 = Ab4[j];
                Ar[4*j] = a4.x; Ar[4*j+1] = a4.y; Ar[4*j+2] = a4.z; Ar[4*j+3] = a4.w;
            }
        }

        v2f st2[32];
        #pragma unroll
        for (int k = 0; k < 32; ++k) st2[k] = (v2f){0.f, 0.f};
        st2[0].x = 1.f;

        #pragma unroll
        for (int l = 0; l < NLQ; ++l) {
            #pragma unroll
            for (int q = 0; q < NQB; ++q) {
                const int M = GT.M[l][q], V = GT.V[l][q];
                const int KD = M >> 1, SW = M & 1;
                int hh = KD; hh |= hh >> 1; hh |= hh >> 2; hh |= hh >> 4;
                const int HB = hh - (hh >> 1);
                float a = Ar[l * NQB + q] + (q < NDQ ? angp[q] : 0.f);
                float sn, cs;
                __sincosf(0.5f * a, &sn, &cs);
                v2f cs2 = {cs, cs};
                v2f sPP = {sn, sn}, sPM = {sn, -sn}, sMP = {-sn, sn}, sMM = {-sn, -sn};
                // sign(i) = parity(i&V) ? +sn : -sn  (R8-verified convention)
                auto COV = [&](int i0) -> v2f {
                    bool p0 = parity6(i0 & V), p1 = parity6((i0 + 1) & V);
                    return p0 ? (p1 ? sPP : sPM) : (p1 ? sMP : sMM);
                };
                if (KD == 0) {          // M==1: partner inside the v2f
                    #pragma unroll
                    for (int k = 0; k < 32; ++k) {
                        v2f ov = __builtin_shufflevector(st2[k], st2[k], 1, 0);
                        st2[k] = __builtin_elementwise_fma(COV(2*k), ov, cs2 * st2[k]);
                    }
                } else {                // pairwise in-place over reg pairs k <-> k^KD
                    #pragma unroll
                    for (int k = 0; k < 32; ++k) {
                        if (k & HB) continue;
                        int kp = k ^ KD;
                        v2f av = st2[k], bv = st2[kp];
                        v2f am = SW ? __builtin_shufflevector(av, av, 1, 0) : av;
                        v2f bm = SW ? __builtin_shufflevector(bv, bv, 1, 0) : bv;
                        st2[k]  = __builtin_elementwise_fma(COV(2*k),  bm, cs2 * av);
                        st2[kp] = __builtin_elementwise_fma(COV(2*kp), am, cs2 * bv);
                    }
                }
            }
        }

        // probs + measurement (sign -1 iff parity(i & W[d]); R8-verified)
        #pragma unroll
        for (int k = 0; k < 32; ++k) st2[k] = st2[k] * st2[k];
        float md[NDQ];
        #pragma unroll
        for (int d = 0; d < NDQ; ++d) {
            const int W = GT.W[d];
            v2f acc = {0.f, 0.f};
            #pragma unroll
            for (int k = 0; k < 32; ++k) {
                v2f sg = { parity6((2*k)     & W) ? -1.f : 1.f,
                           parity6((2*k + 1) & W) ? -1.f : 1.f };
                acc = __builtin_elementwise_fma(sg, st2[k], acc);
            }
            md[d] = acc.x + acc.y;
        }
        float4 mv = {md[0], md[1], md[2], md[3]};
        *(float4*)(as_ + p * 36 + g * 4) = mv;   // meas overwrites ang slots
    }
    __syncthreads();

    // ---- P4: out = w_out.meas + b_out + x; lane=(p=t&7, cs=t>>3) ----
    {
        int p = t & 7, cs = t >> 3;
        float4 m4[8];
        #pragma unroll
        for (int j = 0; j < 8; ++j) m4[j] = *(const float4*)(as_ + p * 36 + 4 * j);
        #pragma unroll 4
        for (int k = 0; k < 32; ++k) {
            int c = cs + 8 * k;
            const float* wr = w_out + c * 32;
            v2f acc = {0.f, 0.f};
            #pragma unroll
            for (int j = 0; j < 8; ++j) {
                float4 w = *(const float4*)(wr + 4 * j);
                acc = __builtin_elementwise_fma((v2f){w.x, w.y}, (v2f){m4[j].x, m4[j].y}, acc);
                acc = __builtin_elementwise_fma((v2f){w.z, w.w}, (v2f){m4[j].z, m4[j].w}, acc);
            }
            float pd = acc.x + acc.y + b_out[c] + xs[p * XPAD + c];
            out[(size_t)(b * NC + c) * NHW + pbase + p] = pd;
        }
    }
}

extern "C" void kernel_launch(void* const* d_in, const int* in_sizes, int n_in,
                              void* d_out, int out_size, void* d_ws, size_t ws_size,
                              hipStream_t stream) {
    const float* x       = (const float*)d_in[0];
    const float* emb     = (const float*)d_in[1];
    const float* gamma   = (const float*)d_in[2];
    const float* beta    = (const float*)d_in[3];
    const float* w_in    = (const float*)d_in[4];
    const float* b_in    = (const float*)d_in[5];
    const float* theta   = (const float*)d_in[6];
    const float* w_style = (const float*)d_in[7];
    const float* b_style = (const float*)d_in[8];
    const float* w_out   = (const float*)d_in[9];
    const float* b_out   = (const float*)d_in[10];
    float* out = (float*)d_out;

    float* ws = (float*)d_ws;
    float* mu = ws;           // 512
    float* rs = ws + 512;     // 512
    float* A  = ws + 1024;    // 3072

    k_pre<<<512 + NB, 256, 0, stream>>>(x, emb, w_style, b_style, theta, mu, rs, A);
    k_main<<<2048, 64, 0, stream>>>(x, gamma, beta, w_in, b_in, A,
                                    w_out, b_out, mu, rs, out);
}

// Round 10
// 138.795 us; speedup vs baseline: 1.2952x; 1.2952x over previous
//
#include <hip/hip_runtime.h>
#include <math.h>

#define NB 16
#define NC 256
#define NHW 1024
#define NE 512
#define NDQ 4
#define NLQ 4
#define NQB 6
#define QDIM 64
#define PIX 16     // pixels per k_main block (64-B aligned tiles)
#define XPAD 260   // xs row stride (floats)

typedef float v2f __attribute__((ext_vector_type(2)));

// ======== constexpr circuit algebra (CNOT ring is GF(2)-linear) ========
constexpr int fwd1(int i) {
    int r = i;
    for (int c = 0; c < NQB; ++c) {
        int t = (c + 1) % NQB;
        if ((r >> (NQB - 1 - c)) & 1) r ^= 1 << (NQB - 1 - t);
    }
    return r;
}
constexpr int fwdl(int s, int l) { for (int i = 0; i < l; ++i) s = fwd1(s); return s; }
constexpr int parity6(int x) { x ^= x >> 4; x ^= x >> 2; x ^= x >> 1; return x & 1; }

// Gate (l,q) acts on storage pairs (s, s^M); sign(i) = parity(i&V) ? +sn : -sn;
// measurement sign for data qubit d: -1 iff parity(i & W[d]).
// (Verified end-to-end by R8 and R9 passing runs.)
struct GateTab { int M[NLQ][NQB]; int V[NLQ][NQB]; int W[NDQ]; };
constexpr GateTab make_tab() {
    GateTab g{};
    for (int l = 0; l < NLQ; ++l)
        for (int q = 0; q < NQB; ++q) {
            int m = 1 << (NQB - 1 - q);
            for (int x = 0; x < QDIM; ++x) if (fwdl(x, l) == m) { g.M[l][q] = x; break; }
            int V = 0;
            for (int t = 0; t < NQB; ++t) V |= ((fwdl(1 << t, l) >> (NQB - 1 - q)) & 1) << t;
            g.V[l][q] = V;
        }
    for (int d = 0; d < NDQ; ++d) {
        int W = 0;
        for (int t = 0; t < NQB; ++t) W |= ((fwdl(1 << t, NLQ) >> (NQB - 1 - d)) & 1) << t;
        g.W[d] = W;
    }
    return g;
}
constexpr GateTab GT = make_tab();

// ---- Kernel 1: fused GroupNorm stats (blk<512) + style matvec (blk>=512) ----
__global__ __launch_bounds__(256) void k_pre(const float* __restrict__ x,
                                             const float* __restrict__ emb,
                                             const float* __restrict__ w_style,
                                             const float* __restrict__ b_style,
                                             const float* __restrict__ theta,
                                             float* __restrict__ mu,
                                             float* __restrict__ rs,
                                             float* __restrict__ A) {
    if (blockIdx.x < 512) {
        int bg = blockIdx.x;
        const float4* xp = (const float4*)(x + (size_t)bg * 8 * NHW);
        float s = 0.f, ss = 0.f;
        for (int i = threadIdx.x; i < 8 * NHW / 4; i += 256) {
            float4 v = xp[i];
            s  += v.x + v.y + v.z + v.w;
            ss += v.x*v.x + v.y*v.y + v.z*v.z + v.w*v.w;
        }
        __shared__ float red0[4], red1[4];
        #pragma unroll
        for (int o = 32; o; o >>= 1) { s += __shfl_down(s, o); ss += __shfl_down(ss, o); }
        int lane = threadIdx.x & 63, w = threadIdx.x >> 6;
        if (lane == 0) { red0[w] = s; red1[w] = ss; }
        __syncthreads();
        if (threadIdx.x == 0) {
            s  = red0[0] + red0[1] + red0[2] + red0[3];
            ss = red1[0] + red1[1] + red1[2] + red1[3];
            float m = s * (1.f / 8192.f);
            float var = ss * (1.f / 8192.f) - m * m;
            mu[bg] = m;
            rs[bg] = rsqrtf(var + 1e-5f);
        }
    } else {
        int b = blockIdx.x - 512;
        __shared__ float es[NE];
        int t = threadIdx.x;
        for (int i = t; i < NE; i += 256) {
            float v = emb[b * NE + i];
            es[i] = v / (1.f + __expf(-v));
        }
        __syncthreads();
        int j0 = t >> 3, sub = t & 7;
        for (int pass = 0; pass < 6; ++pass) {
            int j = pass * 32 + j0;
            const float* wr = w_style + (size_t)j * NE + sub * 64;
            const float* er = es + sub * 64;
            float acc = 0.f;
            #pragma unroll
            for (int i = 0; i < 64; i += 4) {
                float4 w4 = *(const float4*)(wr + i);
                acc = fmaf(w4.x, er[i],   acc);
                acc = fmaf(w4.y, er[i+1], acc);
                acc = fmaf(w4.z, er[i+2], acc);
                acc = fmaf(w4.w, er[i+3], acc);
            }
            acc += __shfl_xor(acc, 1);
            acc += __shfl_xor(acc, 2);
            acc += __shfl_xor(acc, 4);
            if (sub == 0) A[b * 192 + j] = theta[j] + b_style[j] + acc;
        }
    }
}

// ---- Kernel 2: R4 shape + perm-free P3 + pk-packed P2/P4 ----
// grid = 1024 x 256 thr, PIX=16, 4 blocks/CU (grid- and LDS-wise).
// (256,2): VGPR cap 256 so st2 stays in VGPRs (R9's AGPR churn / R6's spill
// both came from over-tight bounds).
__global__ __launch_bounds__(256, 2) void k_main(
    const float* __restrict__ x,
    const float* __restrict__ gamma,
    const float* __restrict__ beta,
    const float* __restrict__ w_in,
    const float* __restrict__ b_in,
    const float* __restrict__ A,
    const float* __restrict__ w_out,
    const float* __restrict__ b_out,
    const float* __restrict__ mu,
    const float* __restrict__ rs,
    float* __restrict__ out) {

    __shared__ float xs[PIX * XPAD];   // [p][c]: normalized h, later raw-x; 16.6 KB
    __shared__ float as_[PIX * 36];    // ang [p][o], later meas [p][o]; 2.3 KB

    int blk = blockIdx.x;
    int b = blk >> 6;
    int pbase = (blk & 63) * PIX;
    int t = threadIdx.x;
    int c0 = t >> 2, f4 = (t & 3) * 4;   // P0/P1: 4 channels (c0+64k) x 4 pixels

    // ---- P0: load x tile to registers (the only x read in this kernel) ----
    float4 xr[4];
    #pragma unroll
    for (int k = 0; k < 4; ++k) {
        int c = c0 + 64 * k;
        xr[k] = *(const float4*)(x + (size_t)(b * NC + c) * NHW + pbase + f4);
    }

    // ---- P1: normalize -> xs [p][c] ----
    #pragma unroll
    for (int k = 0; k < 4; ++k) {
        int c = c0 + 64 * k;
        int g = b * 32 + (c >> 3);
        float sc = rs[g] * gamma[c];
        float sh = fmaf(-mu[g], sc, beta[c]);
        float4 v = xr[k];
        float* bp = xs + f4 * XPAD + c;
        bp[0]        = fmaf(v.x, sc, sh);
        bp[XPAD]     = fmaf(v.y, sc, sh);
        bp[2 * XPAD] = fmaf(v.z, sc, sh);
        bp[3 * XPAD] = fmaf(v.w, sc, sh);
    }
    __syncthreads();

    // ---- P2: ang[p][o]; thread = (2 outputs o0,o0+1; pixel p); pk-FMA ----
    {
        int og = t >> 4, p = t & 15;
        int o0 = og * 2;
        const float* hrow = xs + p * XPAD;
        const float* w0r = w_in + o0 * NC;
        const float* w1r = w_in + (o0 + 1) * NC;
        v2f a0 = {0.f, 0.f}, a1 = {0.f, 0.f};
        #pragma unroll 8
        for (int c = 0; c < NC; c += 4) {
            float4 h = *(const float4*)(hrow + c);
            v2f hlo = {h.x, h.y}, hhi = {h.z, h.w};
            float4 w0 = *(const float4*)(w0r + c);
            float4 w1 = *(const float4*)(w1r + c);
            a0 = __builtin_elementwise_fma((v2f){w0.x, w0.y}, hlo, a0);
            a0 = __builtin_elementwise_fma((v2f){w0.z, w0.w}, hhi, a0);
            a1 = __builtin_elementwise_fma((v2f){w1.x, w1.y}, hlo, a1);
            a1 = __builtin_elementwise_fma((v2f){w1.z, w1.w}, hhi, a1);
        }
        as_[p * 36 + o0]     = a0.x + a0.y + b_in[o0];
        as_[p * 36 + o0 + 1] = a1.x + a1.y + b_in[o0 + 1];
    }
    __syncthreads();

    // ---- stash raw x over xs (P2 consumed the normalized copy) ----
    #pragma unroll
    for (int k = 0; k < 4; ++k) {
        int c = c0 + 64 * k;
        float4 v = xr[k];
        float* bp = xs + f4 * XPAD + c;
        bp[0] = v.x; bp[XPAD] = v.y; bp[2 * XPAD] = v.z; bp[3 * XPAD] = v.w;
    }

    // ---- P3: circuits, threads 0..127 (g = t>>4, p = t&15), perm-free ----
    if (t < 128) {
        int g = t >> 4, p = t & 15;
        float4 angv = *(const float4*)(as_ + p * 36 + g * 4);
        float angp[NDQ] = {angv.x, angv.y, angv.z, angv.w};
        float Ar[24];
        {
            const float4* Ab4 = (const float4*)(A + b * 192 + g * 24);
            #pragma unroll
            for (int j = 0; j < 6; ++j) {
                float4 a4 = Ab4[j];
                Ar[4*j] = a4.x; Ar[4*j+1] = a4.y; Ar[4*j+2] = a4.z; Ar[4*j+3] = a4.w;
            }
        }

        v2f st2[32];
        #pragma unroll
        for (int k = 0; k < 32; ++k) st2[k] = (v2f){0.f, 0.f};
        st2[0].x = 1.f;

        #pragma unroll
        for (int l = 0; l < NLQ; ++l) {
            #pragma unroll
            for (int q = 0; q < NQB; ++q) {
                const int M = GT.M[l][q], V = GT.V[l][q];
                const int KD = M >> 1, SW = M & 1;
                int hh = KD; hh |= hh >> 1; hh |= hh >> 2; hh |= hh >> 4;
                const int HB = hh - (hh >> 1);
                float a = Ar[l * NQB + q] + (q < NDQ ? angp[q] : 0.f);
                float sn, cs;
                __sincosf(0.5f * a, &sn, &cs);
                v2f cs2 = {cs, cs};
                v2f sPP = {sn, sn}, sPM = {sn, -sn}, sMP = {-sn, sn}, sMM = {-sn, -sn};
                auto COV = [&](int i0) -> v2f {
                    bool p0 = parity6(i0 & V), p1 = parity6((i0 + 1) & V);
                    return p0 ? (p1 ? sPP : sPM) : (p1 ? sMP : sMM);
                };
                if (KD == 0) {          // M==1: partner inside the v2f
                    #pragma unroll
                    for (int k = 0; k < 32; ++k) {
                        v2f ov = __builtin_shufflevector(st2[k], st2[k], 1, 0);
                        st2[k] = __builtin_elementwise_fma(COV(2*k), ov, cs2 * st2[k]);
                    }
                } else {                // pairwise in-place over reg pairs k <-> k^KD
                    #pragma unroll
                    for (int k = 0; k < 32; ++k) {
                        if (k & HB) continue;
                        int kp = k ^ KD;
                        v2f av = st2[k], bv = st2[kp];
                        v2f am = SW ? __builtin_shufflevector(av, av, 1, 0) : av;
                        v2f bm = SW ? __builtin_shufflevector(bv, bv, 1, 0) : bv;
                        st2[k]  = __builtin_elementwise_fma(COV(2*k),  bm, cs2 * av);
                        st2[kp] = __builtin_elementwise_fma(COV(2*kp), am, cs2 * bv);
                    }
                }
            }
        }

        // probs + measurement
        #pragma unroll
        for (int k = 0; k < 32; ++k) st2[k] = st2[k] * st2[k];
        float md[NDQ];
        #pragma unroll
        for (int d = 0; d < NDQ; ++d) {
            const int W = GT.W[d];
            v2f acc = {0.f, 0.f};
            #pragma unroll
            for (int k = 0; k < 32; ++k) {
                v2f sg = { parity6((2*k)     & W) ? -1.f : 1.f,
                           parity6((2*k + 1) & W) ? -1.f : 1.f };
                acc = __builtin_elementwise_fma(sg, st2[k], acc);
            }
            md[d] = acc.x + acc.y;
        }
        float4 mv = {md[0], md[1], md[2], md[3]};
        *(float4*)(as_ + p * 36 + g * 4) = mv;   // meas overwrites own ang slot
    }
    __syncthreads();

    // ---- P4: out = w_out.meas + b_out + x; thread = (8 channels, 2 pixels) ----
    {
        int c2 = t >> 3, f2 = (t & 7) * 2;
        // pre-pack meas for the 2 pixels into v2f[32]
        v2f mreg[32];
        #pragma unroll
        for (int j = 0; j < 8; ++j) {
            float4 ma = *(const float4*)(as_ + (f2 + 0) * 36 + 4 * j);
            float4 mb = *(const float4*)(as_ + (f2 + 1) * 36 + 4 * j);
            mreg[4*j + 0] = (v2f){ma.x, mb.x};
            mreg[4*j + 1] = (v2f){ma.y, mb.y};
            mreg[4*j + 2] = (v2f){ma.z, mb.z};
            mreg[4*j + 3] = (v2f){ma.w, mb.w};
        }
        #pragma unroll
        for (int k = 0; k < 8; ++k) {
            int c = c2 + 32 * k;
            const float* wr = w_out + c * 32;
            v2f acc = {0.f, 0.f};
            #pragma unroll
            for (int j = 0; j < 8; ++j) {
                float4 w = *(const float4*)(wr + 4 * j);
                acc = __builtin_elementwise_fma((v2f){w.x, w.x}, mreg[4*j + 0], acc);
                acc = __builtin_elementwise_fma((v2f){w.y, w.y}, mreg[4*j + 1], acc);
                acc = __builtin_elementwise_fma((v2f){w.z, w.z}, mreg[4*j + 2], acc);
                acc = __builtin_elementwise_fma((v2f){w.w, w.w}, mreg[4*j + 3], acc);
            }
            float bo = b_out[c];
            float x0 = xs[(f2 + 0) * XPAD + c];
            float x1 = xs[(f2 + 1) * XPAD + c];
            float2 r = {acc.x + bo + x0, acc.y + bo + x1};
            *(float2*)(out + (size_t)(b * NC + c) * NHW + pbase + f2) = r;
        }
    }
}

extern "C" void kernel_launch(void* const* d_in, const int* in_sizes, int n_in,
                              void* d_out, int out_size, void* d_ws, size_t ws_size,
                              hipStream_t stream) {
    const float* x       = (const float*)d_in[0];
    const float* emb     = (const float*)d_in[1];
    const float* gamma   = (const float*)d_in[2];
    const float* beta    = (const float*)d_in[3];
    const float* w_in    = (const float*)d_in[4];
    const float* b_in    = (const float*)d_in[5];
    const float* theta   = (const float*)d_in[6];
    const float* w_style = (const float*)d_in[7];
    const float* b_style = (const float*)d_in[8];
    const float* w_out   = (const float*)d_in[9];
    const float* b_out   = (const float*)d_in[10];
    float* out = (float*)d_out;

    float* ws = (float*)d_ws;
    float* mu = ws;           // 512
    float* rs = ws + 512;     // 512
    float* A  = ws + 1024;    // 3072

    k_pre<<<512 + NB, 256, 0, stream>>>(x, emb, w_style, b_style, theta, mu, rs, A);
    k_main<<<NB * 64, 256, 0, stream>>>(x, gamma, beta, w_in, b_in, A,
                                        w_out, b_out, mu, rs, out);
}

// Round 11
// 120.380 us; speedup vs baseline: 1.4934x; 1.1530x over previous
//
#include <hip/hip_runtime.h>
#include <math.h>

#define NB 16
#define NC 256
#define NHW 1024
#define NE 512
#define NDQ 4
#define NLQ 4
#define NQB 6
#define QDIM 64
#define PIX 16
#define HSS 264    // hs row stride in bf16 elems (528 B, 16B-aligned, odd-ish banks)

typedef float v2f __attribute__((ext_vector_type(2)));
typedef float f32x4 __attribute__((ext_vector_type(4)));
typedef short bf16x8 __attribute__((ext_vector_type(8)));   // 8 bf16 (4 VGPRs)

__device__ __forceinline__ short f2bf(float v) {   // RNE f32 -> bf16 bits
    unsigned u = __builtin_bit_cast(unsigned, v);
    u += 0x7FFFu + ((u >> 16) & 1u);
    return (short)(u >> 16);
}

// ======== constexpr circuit algebra (CNOT ring is GF(2)-linear) ========
constexpr int fwd1(int i) {
    int r = i;
    for (int c = 0; c < NQB; ++c) {
        int t = (c + 1) % NQB;
        if ((r >> (NQB - 1 - c)) & 1) r ^= 1 << (NQB - 1 - t);
    }
    return r;
}
constexpr int fwdl(int s, int l) { for (int i = 0; i < l; ++i) s = fwd1(s); return s; }
constexpr int parity6(int x) { x ^= x >> 4; x ^= x >> 2; x ^= x >> 1; return x & 1; }

// Verified by R8/R9/R10 passing runs.
struct GateTab { int M[NLQ][NQB]; int V[NLQ][NQB]; int W[NDQ]; };
constexpr GateTab make_tab() {
    GateTab g{};
    for (int l = 0; l < NLQ; ++l)
        for (int q = 0; q < NQB; ++q) {
            int m = 1 << (NQB - 1 - q);
            for (int x = 0; x < QDIM; ++x) if (fwdl(x, l) == m) { g.M[l][q] = x; break; }
            int V = 0;
            for (int t = 0; t < NQB; ++t) V |= ((fwdl(1 << t, l) >> (NQB - 1 - q)) & 1) << t;
            g.V[l][q] = V;
        }
    for (int d = 0; d < NDQ; ++d) {
        int W = 0;
        for (int t = 0; t < NQB; ++t) W |= ((fwdl(1 << t, NLQ) >> (NQB - 1 - d)) & 1) << t;
        g.W[d] = W;
    }
    return g;
}
constexpr GateTab GT = make_tab();

// ---- Kernel 1: stats (blk<512) + style (512..527) + weight bf16 cvt (528) ----
__global__ __launch_bounds__(256) void k_pre(const float* __restrict__ x,
                                             const float* __restrict__ emb,
                                             const float* __restrict__ w_style,
                                             const float* __restrict__ b_style,
                                             const float* __restrict__ theta,
                                             const float* __restrict__ w_in,
                                             const float* __restrict__ w_out,
                                             float* __restrict__ mu,
                                             float* __restrict__ rs,
                                             float* __restrict__ A,
                                             short* __restrict__ wbf) {
    if (blockIdx.x < 512) {
        int bg = blockIdx.x;
        const float4* xp = (const float4*)(x + (size_t)bg * 8 * NHW);
        float s = 0.f, ss = 0.f;
        for (int i = threadIdx.x; i < 8 * NHW / 4; i += 256) {
            float4 v = xp[i];
            s  += v.x + v.y + v.z + v.w;
            ss += v.x*v.x + v.y*v.y + v.z*v.z + v.w*v.w;
        }
        __shared__ float red0[4], red1[4];
        #pragma unroll
        for (int o = 32; o; o >>= 1) { s += __shfl_down(s, o); ss += __shfl_down(ss, o); }
        int lane = threadIdx.x & 63, w = threadIdx.x >> 6;
        if (lane == 0) { red0[w] = s; red1[w] = ss; }
        __syncthreads();
        if (threadIdx.x == 0) {
            s  = red0[0] + red0[1] + red0[2] + red0[3];
            ss = red1[0] + red1[1] + red1[2] + red1[3];
            float m = s * (1.f / 8192.f);
            float var = ss * (1.f / 8192.f) - m * m;
            mu[bg] = m;
            rs[bg] = rsqrtf(var + 1e-5f);
        }
    } else if (blockIdx.x < 512 + NB) {
        int b = blockIdx.x - 512;
        __shared__ float es[NE];
        int t = threadIdx.x;
        for (int i = t; i < NE; i += 256) {
            float v = emb[b * NE + i];
            es[i] = v / (1.f + __expf(-v));
        }
        __syncthreads();
        int j0 = t >> 3, sub = t & 7;
        for (int pass = 0; pass < 6; ++pass) {
            int j = pass * 32 + j0;
            const float* wr = w_style + (size_t)j * NE + sub * 64;
            const float* er = es + sub * 64;
            float acc = 0.f;
            #pragma unroll
            for (int i = 0; i < 64; i += 4) {
                float4 w4 = *(const float4*)(wr + i);
                acc = fmaf(w4.x, er[i],   acc);
                acc = fmaf(w4.y, er[i+1], acc);
                acc = fmaf(w4.z, er[i+2], acc);
                acc = fmaf(w4.w, er[i+3], acc);
            }
            acc += __shfl_xor(acc, 1);
            acc += __shfl_xor(acc, 2);
            acc += __shfl_xor(acc, 4);
            if (sub == 0) A[b * 192 + j] = theta[j] + b_style[j] + acc;
        }
    } else {
        // convert w_in (8192) and w_out (8192) to bf16 once
        for (int i = threadIdx.x; i < 8192; i += 256) wbf[i] = f2bf(w_in[i]);
        for (int i = threadIdx.x; i < 8192; i += 256) wbf[8192 + i] = f2bf(w_out[i]);
    }
}

// ---- Kernel 2: MFMA-ized P2/P4. grid = 1024 x 256 thr, PIX=16 ----
// (256,2): VGPR cap 256 (R6/R9: tighter bounds cause spill/AGPR churn).
__global__ __launch_bounds__(256, 2) void k_main(
    const float* __restrict__ x,
    const float* __restrict__ gamma,
    const float* __restrict__ beta,
    const float* __restrict__ b_in,
    const float* __restrict__ A,
    const short* __restrict__ w_in_bf,    // [o][c] bf16, 32x256
    const short* __restrict__ w_out_bf,   // [c][o] bf16, 256x32
    const float* __restrict__ b_out,
    const float* __restrict__ mu,
    const float* __restrict__ rs,
    float* __restrict__ out) {

    __shared__ short hs[PIX * HSS];     // normalized h bf16 [px][c], 8.25 KB
    __shared__ float xs2[NC * PIX];     // raw x stash [c][px], 16 KB
    __shared__ float as_[PIX * 36];     // ang/meas [px][o], 2.25 KB

    int blk = blockIdx.x;
    int b = blk >> 6;
    int pbase = (blk & 63) * PIX;
    int t = threadIdx.x;
    int lane = t & 63, wv = t >> 6;
    int c0 = t >> 2, f4 = (t & 3) * 4;   // P0/P1: 4 channels (c0+64k) x 4 pixels
    int nn = lane & 15, quad = lane >> 4;

    // ---- P0: load x tile; stash raw immediately in [c][px] layout ----
    float4 xr[4];
    #pragma unroll
    for (int k = 0; k < 4; ++k) {
        int c = c0 + 64 * k;
        xr[k] = *(const float4*)(x + (size_t)(b * NC + c) * NHW + pbase + f4);
        *(float4*)(xs2 + c * PIX + f4) = xr[k];
    }

    // ---- waves 2,3: preload P2 B-fragments (w_in bf16), o-tile per wave ----
    bf16x8 bfrag[8];
    if (wv >= 2) {
        int o = ((wv - 2) << 4) + nn;
        #pragma unroll
        for (int s = 0; s < 8; ++s)
            bfrag[s] = *(const bf16x8*)(w_in_bf + o * NC + s * 32 + quad * 8);
    }

    // ---- P1: normalize -> hs bf16 [px][c] ----
    #pragma unroll
    for (int k = 0; k < 4; ++k) {
        int c = c0 + 64 * k;
        int g = b * 32 + (c >> 3);
        float sc = rs[g] * gamma[c];
        float sh = fmaf(-mu[g], sc, beta[c]);
        float4 v = xr[k];
        hs[(f4 + 0) * HSS + c] = f2bf(fmaf(v.x, sc, sh));
        hs[(f4 + 1) * HSS + c] = f2bf(fmaf(v.y, sc, sh));
        hs[(f4 + 2) * HSS + c] = f2bf(fmaf(v.z, sc, sh));
        hs[(f4 + 3) * HSS + c] = f2bf(fmaf(v.w, sc, sh));
    }
    __syncthreads();

    // ---- P2 (waves 2,3): ang = h @ w_in^T via MFMA 16x16x32, 8 K-steps ----
    if (wv >= 2) {
        f32x4 acc = {0.f, 0.f, 0.f, 0.f};
        #pragma unroll
        for (int s = 0; s < 8; ++s) {
            bf16x8 afr = *(const bf16x8*)(hs + nn * HSS + s * 32 + quad * 8);
            acc = __builtin_amdgcn_mfma_f32_16x16x32_bf16(afr, bfrag[s], acc, 0, 0, 0);
        }
        // D[m=px=quad*4+r][n=o]; add bias, write as_[px][o]
        int o = ((wv - 2) << 4) + nn;
        float bi = b_in[o];
        #pragma unroll
        for (int r = 0; r < 4; ++r)
            as_[(quad * 4 + r) * 36 + o] = acc[r] + bi;
    }
    __syncthreads();

    // ---- P3 (waves 0,1): circuits, perm-free (verified R8-R10) ----
    if (t < 128) {
        int g = t >> 4, p = t & 15;
        float4 angv = *(const float4*)(as_ + p * 36 + g * 4);
        float angp[NDQ] = {angv.x, angv.y, angv.z, angv.w};
        float Ar[24];
        {
            const float4* Ab4 = (const float4*)(A + b * 192 + g * 24);
            #pragma unroll
            for (int j = 0; j < 6; ++j) {
                float4 a4 = Ab4[j];
                Ar[4*j] = a4.x; Ar[4*j+1] = a4.y; Ar[4*j+2] = a4.z; Ar[4*j+3] = a4.w;
            }
        }

        v2f st2[32];
        #pragma unroll
        for (int k = 0; k < 32; ++k) st2[k] = (v2f){0.f, 0.f};
        st2[0].x = 1.f;

        #pragma unroll
        for (int l = 0; l < NLQ; ++l) {
            #pragma unroll
            for (int q = 0; q < NQB; ++q) {
                const int M = GT.M[l][q], V = GT.V[l][q];
                const int KD = M >> 1, SW = M & 1;
                int hh = KD; hh |= hh >> 1; hh |= hh >> 2; hh |= hh >> 4;
                const int HB = hh - (hh >> 1);
                float a = Ar[l * NQB + q] + (q < NDQ ? angp[q] : 0.f);
                float sn, cs;
                __sincosf(0.5f * a, &sn, &cs);
                v2f cs2 = {cs, cs};
                v2f sPP = {sn, sn}, sPM = {sn, -sn}, sMP = {-sn, sn}, sMM = {-sn, -sn};
                auto COV = [&](int i0) -> v2f {
                    bool p0 = parity6(i0 & V), p1 = parity6((i0 + 1) & V);
                    return p0 ? (p1 ? sPP : sPM) : (p1 ? sMP : sMM);
                };
                if (KD == 0) {
                    #pragma unroll
                    for (int k = 0; k < 32; ++k) {
                        v2f ov = __builtin_shufflevector(st2[k], st2[k], 1, 0);
                        st2[k] = __builtin_elementwise_fma(COV(2*k), ov, cs2 * st2[k]);
                    }
                } else {
                    #pragma unroll
                    for (int k = 0; k < 32; ++k) {
                        if (k & HB) continue;
                        int kp = k ^ KD;
                        v2f av = st2[k], bv = st2[kp];
                        v2f am = SW ? __builtin_shufflevector(av, av, 1, 0) : av;
                        v2f bm = SW ? __builtin_shufflevector(bv, bv, 1, 0) : bv;
                        st2[k]  = __builtin_elementwise_fma(COV(2*k),  bm, cs2 * av);
                        st2[kp] = __builtin_elementwise_fma(COV(2*kp), am, cs2 * bv);
                    }
                }
            }
        }

        #pragma unroll
        for (int k = 0; k < 32; ++k) st2[k] = st2[k] * st2[k];
        float md[NDQ];
        #pragma unroll
        for (int d = 0; d < NDQ; ++d) {
            const int W = GT.W[d];
            v2f acc = {0.f, 0.f};
            #pragma unroll
            for (int k = 0; k < 32; ++k) {
                v2f sg = { parity6((2*k)     & W) ? -1.f : 1.f,
                           parity6((2*k + 1) & W) ? -1.f : 1.f };
                acc = __builtin_elementwise_fma(sg, st2[k], acc);
            }
            md[d] = acc.x + acc.y;
        }
        float4 mv = {md[0], md[1], md[2], md[3]};
        *(float4*)(as_ + p * 36 + g * 4) = mv;   // meas overwrites own ang slot
    }
    __syncthreads();

    // ---- P4 (all 4 waves, 4 tiles each): out = meas @ w_out^T + b_out + x ----
    {
        // A-fragment: meas[px=nn][o=quad*8+j], cvt f32->bf16
        float4 m0 = *(const float4*)(as_ + nn * 36 + quad * 8);
        float4 m1 = *(const float4*)(as_ + nn * 36 + quad * 8 + 4);
        bf16x8 afr = { f2bf(m0.x), f2bf(m0.y), f2bf(m0.z), f2bf(m0.w),
                       f2bf(m1.x), f2bf(m1.y), f2bf(m1.z), f2bf(m1.w) };
        #pragma unroll
        for (int ti = 0; ti < 4; ++ti) {
            int tile = wv * 4 + ti;
            int c = tile * 16 + nn;
            bf16x8 bfr = *(const bf16x8*)(w_out_bf + c * 32 + quad * 8);
            f32x4 acc = {0.f, 0.f, 0.f, 0.f};
            acc = __builtin_amdgcn_mfma_f32_16x16x32_bf16(afr, bfr, acc, 0, 0, 0);
            // D[m=px=quad*4+r][n=c]: 4 consecutive px for this c
            float bo = b_out[c];
            float4 x4 = *(const float4*)(xs2 + c * PIX + quad * 4);
            float4 r;
            r.x = acc[0] + bo + x4.x;
            r.y = acc[1] + bo + x4.y;
            r.z = acc[2] + bo + x4.z;
            r.w = acc[3] + bo + x4.w;
            *(float4*)(out + (size_t)(b * NC + c) * NHW + pbase + quad * 4) = r;
        }
    }
}

extern "C" void kernel_launch(void* const* d_in, const int* in_sizes, int n_in,
                              void* d_out, int out_size, void* d_ws, size_t ws_size,
                              hipStream_t stream) {
    const float* x       = (const float*)d_in[0];
    const float* emb     = (const float*)d_in[1];
    const float* gamma   = (const float*)d_in[2];
    const float* beta    = (const float*)d_in[3];
    const float* w_in    = (const float*)d_in[4];
    const float* b_in    = (const float*)d_in[5];
    const float* theta   = (const float*)d_in[6];
    const float* w_style = (const float*)d_in[7];
    const float* b_style = (const float*)d_in[8];
    const float* w_out   = (const float*)d_in[9];
    const float* b_out   = (const float*)d_in[10];
    float* out = (float*)d_out;

    float* ws = (float*)d_ws;
    float* mu = ws;                        // 512
    float* rs = ws + 512;                  // 512
    float* A  = ws + 1024;                 // 3072
    short* wbf = (short*)(ws + 4096);      // 16384 bf16: w_in | w_out

    k_pre<<<512 + NB + 1, 256, 0, stream>>>(x, emb, w_style, b_style, theta,
                                            w_in, w_out, mu, rs, A, wbf);
    k_main<<<NB * 64, 256, 0, stream>>>(x, gamma, beta, b_in, A,
                                        wbf, wbf + 8192, b_out, mu, rs, out);
}

// Round 12
// 120.142 us; speedup vs baseline: 1.4963x; 1.0020x over previous
//
#include <hip/hip_runtime.h>
#include <math.h>

#define NB 16
#define NC 256
#define NHW 1024
#define NE 512
#define NDQ 4
#define NLQ 4
#define NQB 6
#define QDIM 64
#define PIX 16
#define HSS 264    // hs row stride in bf16 elems

typedef float v2f __attribute__((ext_vector_type(2)));
typedef float f32x4 __attribute__((ext_vector_type(4)));
typedef short bf16x8 __attribute__((ext_vector_type(8)));   // 8 bf16 (4 VGPRs)

__device__ __forceinline__ short f2bf(float v) {   // RNE f32 -> bf16 bits
    unsigned u = __builtin_bit_cast(unsigned, v);
    u += 0x7FFFu + ((u >> 16) & 1u);
    return (short)(u >> 16);
}

// ======== constexpr circuit algebra (CNOT ring is GF(2)-linear) ========
constexpr int fwd1(int i) {
    int r = i;
    for (int c = 0; c < NQB; ++c) {
        int t = (c + 1) % NQB;
        if ((r >> (NQB - 1 - c)) & 1) r ^= 1 << (NQB - 1 - t);
    }
    return r;
}
constexpr int fwdl(int s, int l) { for (int i = 0; i < l; ++i) s = fwd1(s); return s; }
constexpr int parity6(int x) { x ^= x >> 4; x ^= x >> 2; x ^= x >> 1; return x & 1; }

// Verified by R8-R11 passing runs.
struct GateTab { int M[NLQ][NQB]; int V[NLQ][NQB]; int W[NDQ]; };
constexpr GateTab make_tab() {
    GateTab g{};
    for (int l = 0; l < NLQ; ++l)
        for (int q = 0; q < NQB; ++q) {
            int m = 1 << (NQB - 1 - q);
            for (int x = 0; x < QDIM; ++x) if (fwdl(x, l) == m) { g.M[l][q] = x; break; }
            int V = 0;
            for (int t = 0; t < NQB; ++t) V |= ((fwdl(1 << t, l) >> (NQB - 1 - q)) & 1) << t;
            g.V[l][q] = V;
        }
    for (int d = 0; d < NDQ; ++d) {
        int W = 0;
        for (int t = 0; t < NQB; ++t) W |= ((fwdl(1 << t, NLQ) >> (NQB - 1 - d)) & 1) << t;
        g.W[d] = W;
    }
    return g;
}
constexpr GateTab GT = make_tab();

// ---- Kernel 1: stats->scale/shift (blk<512) + style (512..527) + w cvt (528) ----
__global__ __launch_bounds__(256) void k_pre(const float* __restrict__ x,
                                             const float* __restrict__ emb,
                                             const float* __restrict__ w_style,
                                             const float* __restrict__ b_style,
                                             const float* __restrict__ theta,
                                             const float* __restrict__ w_in,
                                             const float* __restrict__ w_out,
                                             const float* __restrict__ gamma,
                                             const float* __restrict__ beta,
                                             float* __restrict__ scs,
                                             float* __restrict__ shs,
                                             float* __restrict__ A,
                                             short* __restrict__ wbf) {
    if (blockIdx.x < 512) {
        int bg = blockIdx.x;                 // b*32 + g
        const float4* xp = (const float4*)(x + (size_t)bg * 8 * NHW);
        float s = 0.f, ss = 0.f;
        for (int i = threadIdx.x; i < 8 * NHW / 4; i += 256) {
            float4 v = xp[i];
            s  += v.x + v.y + v.z + v.w;
            ss += v.x*v.x + v.y*v.y + v.z*v.z + v.w*v.w;
        }
        __shared__ float red0[4], red1[4];
        #pragma unroll
        for (int o = 32; o; o >>= 1) { s += __shfl_down(s, o); ss += __shfl_down(ss, o); }
        int lane = threadIdx.x & 63, w = threadIdx.x >> 6;
        if (lane == 0) { red0[w] = s; red1[w] = ss; }
        __syncthreads();
        if (threadIdx.x == 0) {
            s  = red0[0] + red0[1] + red0[2] + red0[3];
            ss = red1[0] + red1[1] + red1[2] + red1[3];
            float m = s * (1.f / 8192.f);
            float rsv = rsqrtf(ss * (1.f / 8192.f) - m * m + 1e-5f);
            int cbase = (bg & 31) * 8;       // channels of this group
            int b = bg >> 5;
            #pragma unroll
            for (int j = 0; j < 8; ++j) {
                int c = cbase + j;
                float sc = rsv * gamma[c];
                scs[b * NC + c] = sc;
                shs[b * NC + c] = fmaf(-m, sc, beta[c]);
            }
        }
    } else if (blockIdx.x < 512 + NB) {
        int b = blockIdx.x - 512;
        __shared__ float es[NE];
        int t = threadIdx.x;
        for (int i = t; i < NE; i += 256) {
            float v = emb[b * NE + i];
            es[i] = v / (1.f + __expf(-v));
        }
        __syncthreads();
        int j0 = t >> 3, sub = t & 7;
        for (int pass = 0; pass < 6; ++pass) {
            int j = pass * 32 + j0;
            const float* wr = w_style + (size_t)j * NE + sub * 64;
            const float* er = es + sub * 64;
            float acc = 0.f;
            #pragma unroll
            for (int i = 0; i < 64; i += 4) {
                float4 w4 = *(const float4*)(wr + i);
                acc = fmaf(w4.x, er[i],   acc);
                acc = fmaf(w4.y, er[i+1], acc);
                acc = fmaf(w4.z, er[i+2], acc);
                acc = fmaf(w4.w, er[i+3], acc);
            }
            acc += __shfl_xor(acc, 1);
            acc += __shfl_xor(acc, 2);
            acc += __shfl_xor(acc, 4);
            if (sub == 0) A[b * 192 + j] = theta[j] + b_style[j] + acc;
        }
    } else {
        for (int i = threadIdx.x; i < 8192; i += 256) wbf[i] = f2bf(w_in[i]);
        for (int i = threadIdx.x; i < 8192; i += 256) wbf[8192 + i] = f2bf(w_out[i]);
    }
}

// ---- Kernel 2: MFMA P2/P4 + register prefetch. grid = 1024 x 256, PIX=16 ----
// (256,2): VGPR cap 256 (tighter bounds caused spill R6 / AGPR churn R9).
__global__ __launch_bounds__(256, 2) void k_main(
    const float* __restrict__ x,
    const float* __restrict__ scs,
    const float* __restrict__ shs,
    const float* __restrict__ b_in,
    const float* __restrict__ A,
    const short* __restrict__ w_in_bf,    // [o][c] bf16, 32x256
    const short* __restrict__ w_out_bf,   // [c][o] bf16, 256x32
    const float* __restrict__ b_out,
    float* __restrict__ out) {

    __shared__ short hs[PIX * HSS];     // normalized h bf16 [px][c], 8.25 KB
    __shared__ float xs2[NC * PIX];     // raw x stash [c][px], 16 KB
    __shared__ float as_[PIX * 36];     // ang/meas [px][o], 2.25 KB

    int blk = blockIdx.x;
    int b = blk >> 6;
    int pbase = (blk & 63) * PIX;
    int t = threadIdx.x;
    int lane = t & 63, wv = t >> 6;
    int c0 = t >> 2, f4 = (t & 3) * 4;   // P0/P1: 4 channels (c0+64k) x 4 pixels
    int nn = lane & 15, quad = lane >> 4;

    // ---- P0: load x tile; stash raw immediately in [c][px] layout ----
    float4 xr[4];
    #pragma unroll
    for (int k = 0; k < 4; ++k) {
        int c = c0 + 64 * k;
        xr[k] = *(const float4*)(x + (size_t)(b * NC + c) * NHW + pbase + f4);
        *(float4*)(xs2 + c * PIX + f4) = xr[k];
    }

    // ---- waves 2,3: preload P2 B-fragments (w_in bf16) ----
    bf16x8 bfrag[8];
    if (wv >= 2) {
        int o = ((wv - 2) << 4) + nn;
        #pragma unroll
        for (int s = 0; s < 8; ++s)
            bfrag[s] = *(const bf16x8*)(w_in_bf + o * NC + s * 32 + quad * 8);
    }

    // ---- waves 0,1: preload style table early (L2 latency hides under P1/P2) ----
    float Ar[24];
    if (wv < 2) {
        int g = (t & 127) >> 4;
        const float4* Ab4 = (const float4*)(A + b * 192 + g * 24);
        #pragma unroll
        for (int j = 0; j < 6; ++j) {
            float4 a4 = Ab4[j];
            Ar[4*j] = a4.x; Ar[4*j+1] = a4.y; Ar[4*j+2] = a4.z; Ar[4*j+3] = a4.w;
        }
    }

    // ---- P1: normalize (precomputed scale/shift) -> hs bf16 [px][c] ----
    #pragma unroll
    for (int k = 0; k < 4; ++k) {
        int c = c0 + 64 * k;
        float sc = scs[b * NC + c];
        float sh = shs[b * NC + c];
        float4 v = xr[k];
        hs[(f4 + 0) * HSS + c] = f2bf(fmaf(v.x, sc, sh));
        hs[(f4 + 1) * HSS + c] = f2bf(fmaf(v.y, sc, sh));
        hs[(f4 + 2) * HSS + c] = f2bf(fmaf(v.z, sc, sh));
        hs[(f4 + 3) * HSS + c] = f2bf(fmaf(v.w, sc, sh));
    }
    __syncthreads();

    // ---- P2 (waves 2,3): ang = h @ w_in^T via MFMA 16x16x32, 8 K-steps ----
    if (wv >= 2) {
        f32x4 acc = {0.f, 0.f, 0.f, 0.f};
        #pragma unroll
        for (int s = 0; s < 8; ++s) {
            bf16x8 afr = *(const bf16x8*)(hs + nn * HSS + s * 32 + quad * 8);
            acc = __builtin_amdgcn_mfma_f32_16x16x32_bf16(afr, bfrag[s], acc, 0, 0, 0);
        }
        int o = ((wv - 2) << 4) + nn;
        float bi = b_in[o];
        #pragma unroll
        for (int r = 0; r < 4; ++r)
            as_[(quad * 4 + r) * 36 + o] = acc[r] + bi;   // D[m=px=quad*4+r][n=o]
    }

    // ---- ALL waves: prefetch P4 B-fragments + b_out now; loads stay in flight
    //      across the P3 phase (waves 2,3 idle there; waves 0,1 busy on VALU) ----
    bf16x8 bfr4[4];
    float  bo4[4];
    #pragma unroll
    for (int ti = 0; ti < 4; ++ti) {
        int c = (wv * 4 + ti) * 16 + nn;
        bfr4[ti] = *(const bf16x8*)(w_out_bf + c * 32 + quad * 8);
        bo4[ti]  = b_out[c];
    }
    __syncthreads();

    // ---- P3 (waves 0,1): circuits, perm-free (verified R8-R11) ----
    if (t < 128) {
        int g = t >> 4, p = t & 15;
        float4 angv = *(const float4*)(as_ + p * 36 + g * 4);
        float angp[NDQ] = {angv.x, angv.y, angv.z, angv.w};

        v2f st2[32];
        #pragma unroll
        for (int k = 0; k < 32; ++k) st2[k] = (v2f){0.f, 0.f};
        st2[0].x = 1.f;

        #pragma unroll
        for (int l = 0; l < NLQ; ++l) {
            #pragma unroll
            for (int q = 0; q < NQB; ++q) {
                const int M = GT.M[l][q], V = GT.V[l][q];
                const int KD = M >> 1, SW = M & 1;
                int hh = KD; hh |= hh >> 1; hh |= hh >> 2; hh |= hh >> 4;
                const int HB = hh - (hh >> 1);
                float a = Ar[l * NQB + q] + (q < NDQ ? angp[q] : 0.f);
                float sn, cs;
                __sincosf(0.5f * a, &sn, &cs);
                v2f cs2 = {cs, cs};
                v2f sPP = {sn, sn}, sPM = {sn, -sn}, sMP = {-sn, sn}, sMM = {-sn, -sn};
                auto COV = [&](int i0) -> v2f {
                    bool p0 = parity6(i0 & V), p1 = parity6((i0 + 1) & V);
                    return p0 ? (p1 ? sPP : sPM) : (p1 ? sMP : sMM);
                };
                if (KD == 0) {
                    #pragma unroll
                    for (int k = 0; k < 32; ++k) {
                        v2f ov = __builtin_shufflevector(st2[k], st2[k], 1, 0);
                        st2[k] = __builtin_elementwise_fma(COV(2*k), ov, cs2 * st2[k]);
                    }
                } else {
                    #pragma unroll
                    for (int k = 0; k < 32; ++k) {
                        if (k & HB) continue;
                        int kp = k ^ KD;
                        v2f av = st2[k], bv = st2[kp];
                        v2f am = SW ? __builtin_shufflevector(av, av, 1, 0) : av;
                        v2f bm = SW ? __builtin_shufflevector(bv, bv, 1, 0) : bv;
                        st2[k]  = __builtin_elementwise_fma(COV(2*k),  bm, cs2 * av);
                        st2[kp] = __builtin_elementwise_fma(COV(2*kp), am, cs2 * bv);
                    }
                }
            }
        }

        #pragma unroll
        for (int k = 0; k < 32; ++k) st2[k] = st2[k] * st2[k];
        float md[NDQ];
        #pragma unroll
        for (int d = 0; d < NDQ; ++d) {
            const int W = GT.W[d];
            v2f acc = {0.f, 0.f};
            #pragma unroll
            for (int k = 0; k < 32; ++k) {
                v2f sg = { parity6((2*k)     & W) ? -1.f : 1.f,
                           parity6((2*k + 1) & W) ? -1.f : 1.f };
                acc = __builtin_elementwise_fma(sg, st2[k], acc);
            }
            md[d] = acc.x + acc.y;
        }
        float4 mv = {md[0], md[1], md[2], md[3]};
        *(float4*)(as_ + p * 36 + g * 4) = mv;   // meas overwrites own ang slot
    }
    __syncthreads();

    // ---- P4 (all waves): out = meas @ w_out^T + b_out + x ----
    {
        float4 m0 = *(const float4*)(as_ + nn * 36 + quad * 8);
        float4 m1 = *(const float4*)(as_ + nn * 36 + quad * 8 + 4);
        bf16x8 afr = { f2bf(m0.x), f2bf(m0.y), f2bf(m0.z), f2bf(m0.w),
                       f2bf(m1.x), f2bf(m1.y), f2bf(m1.z), f2bf(m1.w) };
        #pragma unroll
        for (int ti = 0; ti < 4; ++ti) {
            int c = (wv * 4 + ti) * 16 + nn;
            f32x4 acc = {0.f, 0.f, 0.f, 0.f};
            acc = __builtin_amdgcn_mfma_f32_16x16x32_bf16(afr, bfr4[ti], acc, 0, 0, 0);
            float4 x4 = *(const float4*)(xs2 + c * PIX + quad * 4);
            float4 r;
            r.x = acc[0] + bo4[ti] + x4.x;
            r.y = acc[1] + bo4[ti] + x4.y;
            r.z = acc[2] + bo4[ti] + x4.z;
            r.w = acc[3] + bo4[ti] + x4.w;
            *(float4*)(out + (size_t)(b * NC + c) * NHW + pbase + quad * 4) = r;
        }
    }
}

extern "C" void kernel_launch(void* const* d_in, const int* in_sizes, int n_in,
                              void* d_out, int out_size, void* d_ws, size_t ws_size,
                              hipStream_t stream) {
    const float* x       = (const float*)d_in[0];
    const float* emb     = (const float*)d_in[1];
    const float* gamma   = (const float*)d_in[2];
    const float* beta    = (const float*)d_in[3];
    const float* w_in    = (const float*)d_in[4];
    const float* b_in    = (const float*)d_in[5];
    const float* theta   = (const float*)d_in[6];
    const float* w_style = (const float*)d_in[7];
    const float* b_style = (const float*)d_in[8];
    const float* w_out   = (const float*)d_in[9];
    const float* b_out   = (const float*)d_in[10];
    float* out = (float*)d_out;

    float* ws  = (float*)d_ws;
    float* scs = ws;                        // 4096
    float* shs = ws + 4096;                 // 4096
    float* A   = ws + 8192;                 // 3072
    short* wbf = (short*)(ws + 12288);      // 16384 bf16: w_in | w_out

    k_pre<<<512 + NB + 1, 256, 0, stream>>>(x, emb, w_style, b_style, theta,
                                            w_in, w_out, gamma, beta,
                                            scs, shs, A, wbf);
    k_main<<<NB * 64, 256, 0, stream>>>(x, scs, shs, b_in, A,
                                        wbf, wbf + 8192, b_out, out);
}